// Round 15
// baseline (507.845 us; speedup 1.0000x reference)
//
#include <hip/hip_runtime.h>
#include <hip/hip_fp16.h>
#include <math.h>

#define N_NODES 100000
#define N_EDGES 1600000
#define NF 64
#define ORDER 8
#define NBLK 391          // ceil(N_NODES/256)
#define MAX_ADJ (N_EDGES + 8 * N_NODES)   // padded upper bound
#define NPR (N_NODES / 8)                 // nodes per XCD dst-range, 12500

struct __align__(8) H4 { __half2 a, b; };   // 4 halves

using f16x8 = __attribute__((ext_vector_type(8))) _Float16;
using f32x4 = __attribute__((ext_vector_type(4))) float;

// ---------------- CSR build (once per launch) ----------------

__global__ __launch_bounds__(256) void zero_ints(int* __restrict__ c, int n) {
  int i = blockIdx.x * 256 + threadIdx.x;
  if (i < n) c[i] = 0;
}

// non-temporal dst stream: don't evict counts from L2
__global__ __launch_bounds__(256) void hist_kernel(const int* __restrict__ dst,
                                                   int* __restrict__ counts) {
  int e = blockIdx.x * 256 + threadIdx.x;
  if (e < N_EDGES) atomicAdd(&counts[__builtin_nontemporal_load(&dst[e])], 1);
}

// padded count: round deg up to multiple of 8 (uniform PF spmm loop)
__device__ __forceinline__ int padc(int c) { return (c + 7) & ~7; }

__global__ __launch_bounds__(256) void reduce_counts(const int* __restrict__ counts,
                                                     int* __restrict__ blockSums) {
  int i = blockIdx.x * 256 + threadIdx.x;
  int v = (i < N_NODES) ? padc(counts[i]) : 0;
  #pragma unroll
  for (int m = 1; m < 64; m <<= 1) v += __shfl_xor(v, m, 64);
  __shared__ int s[4];
  if ((threadIdx.x & 63) == 0) s[threadIdx.x >> 6] = v;
  __syncthreads();
  if (threadIdx.x == 0) blockSums[blockIdx.x] = s[0] + s[1] + s[2] + s[3];
}

__global__ __launch_bounds__(512) void scan_partials(const int* __restrict__ blockSums,
                                                     int* __restrict__ blockOffs) {
  __shared__ int s[512];
  int t = threadIdx.x;
  int v = (t < NBLK) ? blockSums[t] : 0;
  s[t] = v;
  __syncthreads();
  for (int off = 1; off < 512; off <<= 1) {
    int u = (t >= off) ? s[t - off] : 0;
    __syncthreads();
    s[t] += u;
    __syncthreads();
  }
  if (t < NBLK) blockOffs[t] = s[t] - v;   // exclusive
}

__global__ __launch_bounds__(256) void scan_blocks(const int* __restrict__ counts,
    const int* __restrict__ blockOffs, int* __restrict__ row_start,
    int* __restrict__ cursor) {
  __shared__ int s[256];
  int t = threadIdx.x;
  int i = blockIdx.x * 256 + t;
  int v = (i < N_NODES) ? padc(counts[i]) : 0;
  s[t] = v;
  __syncthreads();
  for (int off = 1; off < 256; off <<= 1) {
    int u = (t >= off) ? s[t - off] : 0;
    __syncthreads();
    s[t] += u;
    __syncthreads();
  }
  int excl = s[t] - v + blockOffs[blockIdx.x];
  if (i < N_NODES) { row_start[i] = excl; cursor[i] = excl; }
  if (i == N_NODES - 1) row_start[N_NODES] = excl + v;
}

// XCD-partitioned fill, 4 edges/thread, NON-TEMPORAL stream reads:
// dst/src/ew streams bypass L2 LRU so the small hot write-sets (adj region
// ~860 KB/XCD, cursor) stay resident and dirty adj lines coalesce before
// eviction. blockIdx%8 -> XCD round-robin (perf heuristic only).
// packed adj entry: src (17 bits) << 15 | weight as 15-bit fixed point.
__global__ __launch_bounds__(256) void fill_kernel(const int* __restrict__ src,
    const int* __restrict__ dst, const float* __restrict__ ew,
    int* __restrict__ cursor, unsigned int* __restrict__ adj) {
  const int rg = blockIdx.x & 7;
  const int e0 = ((blockIdx.x >> 3) * 256 + threadIdx.x) * 4;
  int d[4];
  bool act[4];
  #pragma unroll
  for (int j = 0; j < 4; ++j) {
    const int e = e0 + j;
    act[j] = (e < N_EDGES);
    d[j] = act[j] ? __builtin_nontemporal_load(&dst[e]) : 0;
    act[j] = act[j] && ((unsigned)(d[j] - rg * NPR) < (unsigned)NPR);
  }
  int pos[4];
  #pragma unroll
  for (int j = 0; j < 4; ++j)
    if (act[j]) pos[j] = atomicAdd(&cursor[d[j]], 1);
  #pragma unroll
  for (int j = 0; j < 4; ++j) {
    if (act[j]) {
      const int e = e0 + j;
      float w = __builtin_nontemporal_load(&ew[e]);
      int s = __builtin_nontemporal_load(&src[e]);
      unsigned int w15 = (unsigned int)rintf(w * 32767.0f);
      adj[pos[j]] = ((unsigned int)s << 15) | w15;
    }
  }
}

// Pack weights fp16 transposed: W0Th[256 n][64 k] = W0[k][n]; W1Th[48 c][256 k] = W1[k][c]
__global__ __launch_bounds__(256) void pack_weights(const float* __restrict__ W0,
    const float* __restrict__ W1, _Float16* __restrict__ W0Th,
    _Float16* __restrict__ W1Th) {
  int t = threadIdx.x;   // one block of 256
  for (int k = 0; k < 64; ++k)
    W0Th[t * 64 + k] = (_Float16)W0[k * 256 + t];
  for (int c = 0; c < 48; ++c) {
    float v = (c < 47) ? W1[t * 47 + c] : 0.0f;
    W1Th[c * 256 + t] = (_Float16)v;
  }
}

// ---------------- propagation ----------------

// x_cur = fp16(X*0.5) ; prop = fp32(X*0.5)
__global__ __launch_bounds__(256) void init_kernel(const float4* __restrict__ X,
    H4* __restrict__ xc, float4* __restrict__ prop, int n4) {
  int i = blockIdx.x * 256 + threadIdx.x;
  if (i >= n4) return;
  float4 v = X[i];
  v.x *= 0.5f; v.y *= 0.5f; v.z *= 0.5f; v.w *= 0.5f;
  prop[i] = v;
  H4 h;
  h.a = __floats2half2_rn(v.x, v.y);
  h.b = __floats2half2_rn(v.z, v.w);
  xc[i] = h;
}

// gather-sum per dst node: 32 lanes/node, half2/lane, fp32 accumulate.
// Rows padded to 8 -> uniform batches; 2-deep batch pipeline (16 gathers in flight).
template<bool ACC>
__global__ __launch_bounds__(256) void spmm_csr(const __half2* __restrict__ x,
    const int* __restrict__ row_start, const unsigned int* __restrict__ adj,
    __half2* __restrict__ xn, float2* __restrict__ prop) {
  const int node = blockIdx.x * 8 + (threadIdx.x >> 5);   // 100000 % 8 == 0
  const int f2 = threadIdx.x & 31;
  const int beg = row_start[node];
  const int nb = (row_start[node + 1] - beg) >> 3;
  const size_t o = (size_t)node * 32 + f2;
  float2 xin;
  if (ACC) xin = __half22float2(x[o]);
  float2 a0 = make_float2(0.f, 0.f), a1 = a0;

  unsigned int e0[8] = {0}, e1[8] = {0};
  __half2 v0[8], v1[8];
  if (nb > 0) {
    #pragma unroll
    for (int j = 0; j < 8; ++j) e0[j] = adj[beg + j];
    #pragma unroll
    for (int j = 0; j < 8; ++j) v0[j] = x[(size_t)(e0[j] >> 15) * 32 + f2];
  }
  if (nb > 1) {
    #pragma unroll
    for (int j = 0; j < 8; ++j) e1[j] = adj[beg + 8 + j];
    #pragma unroll
    for (int j = 0; j < 8; ++j) v1[j] = x[(size_t)(e1[j] >> 15) * 32 + f2];
  }
  for (int b = 0; b < nb; ++b) {
    #pragma unroll
    for (int j = 0; j < 8; ++j) {
      float w = (float)(e0[j] & 0x7fffu) * (1.0f / 32767.0f);
      float2 f = __half22float2(v0[j]);
      if (j & 1) { a1.x = fmaf(f.x, w, a1.x); a1.y = fmaf(f.y, w, a1.y); }
      else       { a0.x = fmaf(f.x, w, a0.x); a0.y = fmaf(f.y, w, a0.y); }
    }
    #pragma unroll
    for (int j = 0; j < 8; ++j) { e0[j] = e1[j]; v0[j] = v1[j]; }
    if (b + 2 < nb) {
      const int q = beg + 8 * (b + 2);
      #pragma unroll
      for (int j = 0; j < 8; ++j) e1[j] = adj[q + j];
      #pragma unroll
      for (int j = 0; j < 8; ++j) v1[j] = x[(size_t)(e1[j] >> 15) * 32 + f2];
    }
  }
  a0.x += a1.x; a0.y += a1.y;
  xn[o] = __floats2half2_rn(a0.x, a0.y);
  if (ACC) {
    float2 pr = prop[o];
    pr.x += xin.x + a0.x;
    pr.y += xin.y + a0.y;
    prop[o] = pr;
  }
}

// ---------------- fused tail, MFMA fp16 ----------------
__global__ __launch_bounds__(256) void tail_kernel(
    const float* __restrict__ prop, const float* __restrict__ b0,
    const _Float16* __restrict__ W0Th, const _Float16* __restrict__ W1Th,
    const float* __restrict__ b1, float* __restrict__ out) {
  __shared__ __align__(16) _Float16 sXp[32][72];
  __shared__ __align__(16) _Float16 sH[32][264];
  __shared__ float sPart[32][8];
  __shared__ float sHinv[32];

  const int t = threadIdx.x;
  const int lane = t & 63;
  const int w = t >> 6;
  const int l15 = lane & 15;
  const int l4 = lane >> 4;
  const int base = blockIdx.x * 32;   // 3125 * 32 == 100000 exactly

  #pragma unroll
  for (int it = 0; it < 8; ++it) {
    const int nb = it * 4 + w;
    float v = prop[(size_t)(base + nb) * NF + lane];
    float ss = v * v;
    #pragma unroll
    for (int m = 1; m < 64; m <<= 1) ss += __shfl_xor(ss, m, 64);
    float nrm = sqrtf(ss) * (1.0f / 9.0f);
    float scale = (1.0f / 9.0f) / (1e-12f + nrm);
    sXp[nb][lane] = (_Float16)(v * scale);
  }
  __syncthreads();

  f32x4 acc1[2][4];
  #pragma unroll
  for (int j = 0; j < 4; ++j) {
    float bv = b0[(w * 4 + j) * 16 + l15];
    #pragma unroll
    for (int mt = 0; mt < 2; ++mt)
      acc1[mt][j] = (f32x4){bv, bv, bv, bv};
  }
  #pragma unroll
  for (int ks = 0; ks < 2; ++ks) {
    const int koff = l4 * 8 + ks * 32;
    f16x8 a0 = *(const f16x8*)&sXp[l15][koff];
    f16x8 a1 = *(const f16x8*)&sXp[16 + l15][koff];
    #pragma unroll
    for (int j = 0; j < 4; ++j) {
      f16x8 b = *(const f16x8*)&W0Th[(size_t)((w * 4 + j) * 16 + l15) * 64 + koff];
      acc1[0][j] = __builtin_amdgcn_mfma_f32_16x16x32_f16(a0, b, acc1[0][j], 0, 0, 0);
      acc1[1][j] = __builtin_amdgcn_mfma_f32_16x16x32_f16(a1, b, acc1[1][j], 0, 0, 0);
    }
  }

  #pragma unroll
  for (int mt = 0; mt < 2; ++mt) {
    #pragma unroll
    for (int r = 0; r < 4; ++r) {
      float s = 0.0f;
      #pragma unroll
      for (int j = 0; j < 4; ++j) {
        float x = fmaxf(acc1[mt][j][r], 0.0f);
        acc1[mt][j][r] = x;
        s = fmaf(x, x, s);
      }
      #pragma unroll
      for (int m = 1; m < 16; m <<= 1) s += __shfl_xor(s, m, 64);
      if (l15 == 0) sPart[mt * 16 + l4 * 4 + r][w] = s;
    }
  }
  __syncthreads();

  if (t < 32) {
    float s = sPart[t][0] + sPart[t][1] + sPart[t][2] + sPart[t][3];
    sHinv[t] = 1.0f / (1e-12f + sqrtf(s));
  }
  __syncthreads();

  #pragma unroll
  for (int mt = 0; mt < 2; ++mt) {
    #pragma unroll
    for (int r = 0; r < 4; ++r) {
      const int row = mt * 16 + l4 * 4 + r;
      const float sc = sHinv[row];
      #pragma unroll
      for (int j = 0; j < 4; ++j)
        sH[row][(w * 4 + j) * 16 + l15] = (_Float16)(acc1[mt][j][r] * sc);
    }
  }
  __syncthreads();

  if (w < 3) {
    const int c = w * 16 + l15;
    float bv = (c < 47) ? b1[c] : 0.0f;
    f32x4 acc2[2];
    acc2[0] = (f32x4){bv, bv, bv, bv};
    acc2[1] = (f32x4){bv, bv, bv, bv};
    #pragma unroll
    for (int ks = 0; ks < 8; ++ks) {
      const int koff = l4 * 8 + ks * 32;
      f16x8 b = *(const f16x8*)&W1Th[(size_t)(w * 16 + l15) * 256 + koff];
      f16x8 a0 = *(const f16x8*)&sH[l15][koff];
      f16x8 a1 = *(const f16x8*)&sH[16 + l15][koff];
      acc2[0] = __builtin_amdgcn_mfma_f32_16x16x32_f16(a0, b, acc2[0], 0, 0, 0);
      acc2[1] = __builtin_amdgcn_mfma_f32_16x16x32_f16(a1, b, acc2[1], 0, 0, 0);
    }
    if (c < 47) {
      #pragma unroll
      for (int mt = 0; mt < 2; ++mt) {
        #pragma unroll
        for (int r = 0; r < 4; ++r) {
          const int node = base + mt * 16 + l4 * 4 + r;
          out[(size_t)node * 47 + c] = acc2[mt][r];
        }
      }
    }
  }
}

extern "C" void kernel_launch(void* const* d_in, const int* in_sizes, int n_in,
                              void* d_out, int out_size, void* d_ws, size_t ws_size,
                              hipStream_t stream) {
  (void)in_sizes; (void)n_in; (void)out_size; (void)ws_size;
  const float* X   = (const float*)d_in[0];
  const int*   src = (const int*)d_in[1];
  const int*   dst = (const int*)d_in[2];
  const float* ew  = (const float*)d_in[3];
  const float* W0  = (const float*)d_in[4];
  const float* b0  = (const float*)d_in[5];
  const float* W1  = (const float*)d_in[6];
  const float* b1  = (const float*)d_in[7];
  float* out = (float*)d_out;

  const size_t nf = (size_t)N_NODES * NF;    // 6.4M elements
  __half* bufA = (__half*)d_ws;              // 12.8 MB
  __half* bufB = bufA + nf;                  // 12.8 MB
  float*  prop = (float*)(bufB + nf);        // 25.6 MB
  int* counts     = (int*)(prop + nf);
  int* row_start  = counts + N_NODES;        // N_NODES+1
  int* cursor     = row_start + (N_NODES + 1);
  int* blockSums  = cursor + N_NODES;
  int* blockOffs  = blockSums + NBLK;
  _Float16* W0Th  = (_Float16*)(((uintptr_t)(blockOffs + NBLK) + 15) & ~(uintptr_t)15);
  _Float16* W1Th  = W0Th + 256 * 64;
  unsigned int* adj = (unsigned int*)(((uintptr_t)(W1Th + 48 * 256) + 15) & ~(uintptr_t)15);

  const int eblocks = (N_EDGES + 255) / 256;
  const int fblocks = (N_EDGES + 1023) / 1024;   // 4 edges/thread

  zero_ints<<<NBLK, 256, 0, stream>>>(counts, N_NODES);
  hipMemsetAsync(adj, 0, (size_t)MAX_ADJ * 4, stream);   // pad entries = (src 0, w 0)
  hist_kernel<<<eblocks, 256, 0, stream>>>(dst, counts);
  reduce_counts<<<NBLK, 256, 0, stream>>>(counts, blockSums);
  scan_partials<<<1, 512, 0, stream>>>(blockSums, blockOffs);
  scan_blocks<<<NBLK, 256, 0, stream>>>(counts, blockOffs, row_start, cursor);
  fill_kernel<<<8 * fblocks, 256, 0, stream>>>(src, dst, ew, cursor, adj);
  pack_weights<<<1, 256, 0, stream>>>(W0, W1, W0Th, W1Th);

  const int n4 = (int)(nf / 4);
  init_kernel<<<(n4 + 255) / 256, 256, 0, stream>>>(
      (const float4*)X, (H4*)bufA, (float4*)prop, n4);

  __half* xc = bufA;
  __half* xn = bufB;
  for (int r = 0; r < ORDER; ++r) {
    if (r & 1) {
      spmm_csr<true><<<N_NODES / 8, 256, 0, stream>>>(
          (const __half2*)xc, row_start, adj, (__half2*)xn, (float2*)prop);
    } else {
      spmm_csr<false><<<N_NODES / 8, 256, 0, stream>>>(
          (const __half2*)xc, row_start, adj, (__half2*)xn, (float2*)prop);
    }
    __half* tmp = xc; xc = xn; xn = tmp;
  }

  tail_kernel<<<N_NODES / 32, 256, 0, stream>>>(prop, b0, W0Th, W1Th, b1, out);
}

// Round 16
// 482.155 us; speedup vs baseline: 1.0533x; 1.0533x over previous
//
#include <hip/hip_runtime.h>
#include <hip/hip_fp16.h>
#include <math.h>

#define N_NODES 100000
#define N_EDGES 1600000
#define NF 64
#define ORDER 8
#define NBLK 391          // ceil(N_NODES/256)
#define MAX_ADJ (N_EDGES + 8 * N_NODES)   // padded upper bound
#define NPR (N_NODES / 8)                 // nodes per XCD dst-range, 12500

struct __align__(8) H4 { __half2 a, b; };   // 4 halves

using f16x8 = __attribute__((ext_vector_type(8))) _Float16;
using f32x4 = __attribute__((ext_vector_type(4))) float;

// ---------------- CSR build (once per launch) ----------------

__global__ __launch_bounds__(256) void zero_ints(int* __restrict__ c, int n) {
  int i = blockIdx.x * 256 + threadIdx.x;
  if (i < n) c[i] = 0;
}

__global__ __launch_bounds__(256) void hist_kernel(const int* __restrict__ dst,
                                                   int* __restrict__ counts) {
  int e = blockIdx.x * 256 + threadIdx.x;
  if (e < N_EDGES) atomicAdd(&counts[dst[e]], 1);
}

// padded count: round deg up to multiple of 8 (uniform PF spmm loop)
__device__ __forceinline__ int padc(int c) { return (c + 7) & ~7; }

__global__ __launch_bounds__(256) void reduce_counts(const int* __restrict__ counts,
                                                     int* __restrict__ blockSums) {
  int i = blockIdx.x * 256 + threadIdx.x;
  int v = (i < N_NODES) ? padc(counts[i]) : 0;
  #pragma unroll
  for (int m = 1; m < 64; m <<= 1) v += __shfl_xor(v, m, 64);
  __shared__ int s[4];
  if ((threadIdx.x & 63) == 0) s[threadIdx.x >> 6] = v;
  __syncthreads();
  if (threadIdx.x == 0) blockSums[blockIdx.x] = s[0] + s[1] + s[2] + s[3];
}

__global__ __launch_bounds__(512) void scan_partials(const int* __restrict__ blockSums,
                                                     int* __restrict__ blockOffs) {
  __shared__ int s[512];
  int t = threadIdx.x;
  int v = (t < NBLK) ? blockSums[t] : 0;
  s[t] = v;
  __syncthreads();
  for (int off = 1; off < 512; off <<= 1) {
    int u = (t >= off) ? s[t - off] : 0;
    __syncthreads();
    s[t] += u;
    __syncthreads();
  }
  if (t < NBLK) blockOffs[t] = s[t] - v;   // exclusive
}

__global__ __launch_bounds__(256) void scan_blocks(const int* __restrict__ counts,
    const int* __restrict__ blockOffs, int* __restrict__ row_start,
    int* __restrict__ cursor) {
  __shared__ int s[256];
  int t = threadIdx.x;
  int i = blockIdx.x * 256 + t;
  int v = (i < N_NODES) ? padc(counts[i]) : 0;
  s[t] = v;
  __syncthreads();
  for (int off = 1; off < 256; off <<= 1) {
    int u = (t >= off) ? s[t - off] : 0;
    __syncthreads();
    s[t] += u;
    __syncthreads();
  }
  int excl = s[t] - v + blockOffs[blockIdx.x];
  if (i < N_NODES) { row_start[i] = excl; cursor[i] = excl; }
  if (i == N_NODES - 1) row_start[N_NODES] = excl + v;
}

// XCD-partitioned fill (R12 version — measured best at 71 us): block handles
// chunk blockIdx>>3, dst-range blockIdx&7. blockIdx%8 -> XCD round-robin, so
// each cursor line / adj region is touched by exactly one XCD (perf heuristic
// only; correctness holds for any mapping since atomics are device-scope).
// packed adj entry: src (17 bits) << 15 | weight as 15-bit fixed point.
__global__ __launch_bounds__(256) void fill_kernel(const int* __restrict__ src,
    const int* __restrict__ dst, const float* __restrict__ ew,
    int* __restrict__ cursor, unsigned int* __restrict__ adj) {
  const int rg = blockIdx.x & 7;
  const int e = (blockIdx.x >> 3) * 256 + threadIdx.x;
  if (e >= N_EDGES) return;
  int d = dst[e];
  if ((unsigned)(d - rg * NPR) >= (unsigned)NPR) return;
  int pos = atomicAdd(&cursor[d], 1);
  unsigned int w15 = (unsigned int)rintf(ew[e] * 32767.0f);
  adj[pos] = ((unsigned int)src[e] << 15) | w15;
}

// Pack weights fp16 transposed: W0Th[256 n][64 k] = W0[k][n]; W1Th[48 c][256 k] = W1[k][c]
__global__ __launch_bounds__(256) void pack_weights(const float* __restrict__ W0,
    const float* __restrict__ W1, _Float16* __restrict__ W0Th,
    _Float16* __restrict__ W1Th) {
  int t = threadIdx.x;   // one block of 256
  for (int k = 0; k < 64; ++k)
    W0Th[t * 64 + k] = (_Float16)W0[k * 256 + t];
  for (int c = 0; c < 48; ++c) {
    float v = (c < 47) ? W1[t * 47 + c] : 0.0f;
    W1Th[c * 256 + t] = (_Float16)v;
  }
}

// ---------------- propagation ----------------

// x_cur = fp16(X*0.5) ; prop = fp32(X*0.5)
__global__ __launch_bounds__(256) void init_kernel(const float4* __restrict__ X,
    H4* __restrict__ xc, float4* __restrict__ prop, int n4) {
  int i = blockIdx.x * 256 + threadIdx.x;
  if (i >= n4) return;
  float4 v = X[i];
  v.x *= 0.5f; v.y *= 0.5f; v.z *= 0.5f; v.w *= 0.5f;
  prop[i] = v;
  H4 h;
  h.a = __floats2half2_rn(v.x, v.y);
  h.b = __floats2half2_rn(v.z, v.w);
  xc[i] = h;
}

// gather-sum per dst node: 32 lanes/node, half2/lane, fp32 accumulate.
// Rows padded to 8 -> uniform batches; 2-deep batch pipeline (16 gathers in flight).
// ACC: fold prop += x_in + x_out (odd rounds). WX: write xn (skipped on final round).
template<bool ACC, bool WX>
__global__ __launch_bounds__(256) void spmm_csr(const __half2* __restrict__ x,
    const int* __restrict__ row_start, const unsigned int* __restrict__ adj,
    __half2* __restrict__ xn, float2* __restrict__ prop) {
  const int node = blockIdx.x * 8 + (threadIdx.x >> 5);   // 100000 % 8 == 0
  const int f2 = threadIdx.x & 31;
  const int beg = row_start[node];
  const int nb = (row_start[node + 1] - beg) >> 3;
  const size_t o = (size_t)node * 32 + f2;
  float2 xin;
  if (ACC) xin = __half22float2(x[o]);
  float2 a0 = make_float2(0.f, 0.f), a1 = a0;

  unsigned int e0[8] = {0}, e1[8] = {0};
  __half2 v0[8], v1[8];
  if (nb > 0) {
    #pragma unroll
    for (int j = 0; j < 8; ++j) e0[j] = adj[beg + j];
    #pragma unroll
    for (int j = 0; j < 8; ++j) v0[j] = x[(size_t)(e0[j] >> 15) * 32 + f2];
  }
  if (nb > 1) {
    #pragma unroll
    for (int j = 0; j < 8; ++j) e1[j] = adj[beg + 8 + j];
    #pragma unroll
    for (int j = 0; j < 8; ++j) v1[j] = x[(size_t)(e1[j] >> 15) * 32 + f2];
  }
  for (int b = 0; b < nb; ++b) {
    #pragma unroll
    for (int j = 0; j < 8; ++j) {
      float w = (float)(e0[j] & 0x7fffu) * (1.0f / 32767.0f);
      float2 f = __half22float2(v0[j]);
      if (j & 1) { a1.x = fmaf(f.x, w, a1.x); a1.y = fmaf(f.y, w, a1.y); }
      else       { a0.x = fmaf(f.x, w, a0.x); a0.y = fmaf(f.y, w, a0.y); }
    }
    #pragma unroll
    for (int j = 0; j < 8; ++j) { e0[j] = e1[j]; v0[j] = v1[j]; }
    if (b + 2 < nb) {
      const int q = beg + 8 * (b + 2);
      #pragma unroll
      for (int j = 0; j < 8; ++j) e1[j] = adj[q + j];
      #pragma unroll
      for (int j = 0; j < 8; ++j) v1[j] = x[(size_t)(e1[j] >> 15) * 32 + f2];
    }
  }
  a0.x += a1.x; a0.y += a1.y;
  if (WX) xn[o] = __floats2half2_rn(a0.x, a0.y);
  if (ACC) {
    float2 pr = prop[o];
    pr.x += xin.x + a0.x;
    pr.y += xin.y + a0.y;
    prop[o] = pr;
  }
}

// ---------------- fused tail, MFMA fp16 ----------------
__global__ __launch_bounds__(256) void tail_kernel(
    const float* __restrict__ prop, const float* __restrict__ b0,
    const _Float16* __restrict__ W0Th, const _Float16* __restrict__ W1Th,
    const float* __restrict__ b1, float* __restrict__ out) {
  __shared__ __align__(16) _Float16 sXp[32][72];
  __shared__ __align__(16) _Float16 sH[32][264];
  __shared__ float sPart[32][8];
  __shared__ float sHinv[32];

  const int t = threadIdx.x;
  const int lane = t & 63;
  const int w = t >> 6;
  const int l15 = lane & 15;
  const int l4 = lane >> 4;
  const int base = blockIdx.x * 32;   // 3125 * 32 == 100000 exactly

  #pragma unroll
  for (int it = 0; it < 8; ++it) {
    const int nb = it * 4 + w;
    float v = prop[(size_t)(base + nb) * NF + lane];
    float ss = v * v;
    #pragma unroll
    for (int m = 1; m < 64; m <<= 1) ss += __shfl_xor(ss, m, 64);
    float nrm = sqrtf(ss) * (1.0f / 9.0f);
    float scale = (1.0f / 9.0f) / (1e-12f + nrm);
    sXp[nb][lane] = (_Float16)(v * scale);
  }
  __syncthreads();

  f32x4 acc1[2][4];
  #pragma unroll
  for (int j = 0; j < 4; ++j) {
    float bv = b0[(w * 4 + j) * 16 + l15];
    #pragma unroll
    for (int mt = 0; mt < 2; ++mt)
      acc1[mt][j] = (f32x4){bv, bv, bv, bv};
  }
  #pragma unroll
  for (int ks = 0; ks < 2; ++ks) {
    const int koff = l4 * 8 + ks * 32;
    f16x8 a0 = *(const f16x8*)&sXp[l15][koff];
    f16x8 a1 = *(const f16x8*)&sXp[16 + l15][koff];
    #pragma unroll
    for (int j = 0; j < 4; ++j) {
      f16x8 b = *(const f16x8*)&W0Th[(size_t)((w * 4 + j) * 16 + l15) * 64 + koff];
      acc1[0][j] = __builtin_amdgcn_mfma_f32_16x16x32_f16(a0, b, acc1[0][j], 0, 0, 0);
      acc1[1][j] = __builtin_amdgcn_mfma_f32_16x16x32_f16(a1, b, acc1[1][j], 0, 0, 0);
    }
  }

  #pragma unroll
  for (int mt = 0; mt < 2; ++mt) {
    #pragma unroll
    for (int r = 0; r < 4; ++r) {
      float s = 0.0f;
      #pragma unroll
      for (int j = 0; j < 4; ++j) {
        float x = fmaxf(acc1[mt][j][r], 0.0f);
        acc1[mt][j][r] = x;
        s = fmaf(x, x, s);
      }
      #pragma unroll
      for (int m = 1; m < 16; m <<= 1) s += __shfl_xor(s, m, 64);
      if (l15 == 0) sPart[mt * 16 + l4 * 4 + r][w] = s;
    }
  }
  __syncthreads();

  if (t < 32) {
    float s = sPart[t][0] + sPart[t][1] + sPart[t][2] + sPart[t][3];
    sHinv[t] = 1.0f / (1e-12f + sqrtf(s));
  }
  __syncthreads();

  #pragma unroll
  for (int mt = 0; mt < 2; ++mt) {
    #pragma unroll
    for (int r = 0; r < 4; ++r) {
      const int row = mt * 16 + l4 * 4 + r;
      const float sc = sHinv[row];
      #pragma unroll
      for (int j = 0; j < 4; ++j)
        sH[row][(w * 4 + j) * 16 + l15] = (_Float16)(acc1[mt][j][r] * sc);
    }
  }
  __syncthreads();

  if (w < 3) {
    const int c = w * 16 + l15;
    float bv = (c < 47) ? b1[c] : 0.0f;
    f32x4 acc2[2];
    acc2[0] = (f32x4){bv, bv, bv, bv};
    acc2[1] = (f32x4){bv, bv, bv, bv};
    #pragma unroll
    for (int ks = 0; ks < 8; ++ks) {
      const int koff = l4 * 8 + ks * 32;
      f16x8 b = *(const f16x8*)&W1Th[(size_t)(w * 16 + l15) * 256 + koff];
      f16x8 a0 = *(const f16x8*)&sH[l15][koff];
      f16x8 a1 = *(const f16x8*)&sH[16 + l15][koff];
      acc2[0] = __builtin_amdgcn_mfma_f32_16x16x32_f16(a0, b, acc2[0], 0, 0, 0);
      acc2[1] = __builtin_amdgcn_mfma_f32_16x16x32_f16(a1, b, acc2[1], 0, 0, 0);
    }
    if (c < 47) {
      #pragma unroll
      for (int mt = 0; mt < 2; ++mt) {
        #pragma unroll
        for (int r = 0; r < 4; ++r) {
          const int node = base + mt * 16 + l4 * 4 + r;
          out[(size_t)node * 47 + c] = acc2[mt][r];
        }
      }
    }
  }
}

extern "C" void kernel_launch(void* const* d_in, const int* in_sizes, int n_in,
                              void* d_out, int out_size, void* d_ws, size_t ws_size,
                              hipStream_t stream) {
  (void)in_sizes; (void)n_in; (void)out_size; (void)ws_size;
  const float* X   = (const float*)d_in[0];
  const int*   src = (const int*)d_in[1];
  const int*   dst = (const int*)d_in[2];
  const float* ew  = (const float*)d_in[3];
  const float* W0  = (const float*)d_in[4];
  const float* b0  = (const float*)d_in[5];
  const float* W1  = (const float*)d_in[6];
  const float* b1  = (const float*)d_in[7];
  float* out = (float*)d_out;

  const size_t nf = (size_t)N_NODES * NF;    // 6.4M elements
  __half* bufA = (__half*)d_ws;              // 12.8 MB
  __half* bufB = bufA + nf;                  // 12.8 MB
  float*  prop = (float*)(bufB + nf);        // 25.6 MB
  int* counts     = (int*)(prop + nf);
  int* row_start  = counts + N_NODES;        // N_NODES+1
  int* cursor     = row_start + (N_NODES + 1);
  int* blockSums  = cursor + N_NODES;
  int* blockOffs  = blockSums + NBLK;
  _Float16* W0Th  = (_Float16*)(((uintptr_t)(blockOffs + NBLK) + 15) & ~(uintptr_t)15);
  _Float16* W1Th  = W0Th + 256 * 64;
  unsigned int* adj = (unsigned int*)(((uintptr_t)(W1Th + 48 * 256) + 15) & ~(uintptr_t)15);

  const int eblocks = (N_EDGES + 255) / 256;

  zero_ints<<<NBLK, 256, 0, stream>>>(counts, N_NODES);
  hipMemsetAsync(adj, 0, (size_t)MAX_ADJ * 4, stream);   // pad entries = (src 0, w 0)
  hist_kernel<<<eblocks, 256, 0, stream>>>(dst, counts);
  reduce_counts<<<NBLK, 256, 0, stream>>>(counts, blockSums);
  scan_partials<<<1, 512, 0, stream>>>(blockSums, blockOffs);
  scan_blocks<<<NBLK, 256, 0, stream>>>(counts, blockOffs, row_start, cursor);
  fill_kernel<<<8 * eblocks, 256, 0, stream>>>(src, dst, ew, cursor, adj);
  pack_weights<<<1, 256, 0, stream>>>(W0, W1, W0Th, W1Th);

  const int n4 = (int)(nf / 4);
  init_kernel<<<(n4 + 255) / 256, 256, 0, stream>>>(
      (const float4*)X, (H4*)bufA, (float4*)prop, n4);

  __half* xc = bufA;
  __half* xn = bufB;
  for (int r = 0; r < ORDER; ++r) {
    if (r == ORDER - 1) {
      spmm_csr<true, false><<<N_NODES / 8, 256, 0, stream>>>(
          (const __half2*)xc, row_start, adj, (__half2*)xn, (float2*)prop);
    } else if (r & 1) {
      spmm_csr<true, true><<<N_NODES / 8, 256, 0, stream>>>(
          (const __half2*)xc, row_start, adj, (__half2*)xn, (float2*)prop);
    } else {
      spmm_csr<false, true><<<N_NODES / 8, 256, 0, stream>>>(
          (const __half2*)xc, row_start, adj, (__half2*)xn, (float2*)prop);
    }
    __half* tmp = xc; xc = xn; xn = tmp;
  }

  tail_kernel<<<N_NODES / 32, 256, 0, stream>>>(prop, b0, W0Th, W1Th, b1, out);
}